// Round 2
// baseline (1341.637 us; speedup 1.0000x reference)
//
#include <hip/hip_runtime.h>
#include <hip/hip_bf16.h>

// RGCN 2-layer + global mean pool + log_softmax.
// N=100000 nodes, E=1.6M edges, R=8 relations, 64->64->16 channels.
//
// Layer 1: h = relu(x @ root1 + b1 + sum_r (mean-agg_r x) @ W1[r])
//   computed as: per relation r, xt = x @ W1[r] (GEMM), then scatter
//   hmsg[dst] += xt[src] * inv[r][dst] (f32 atomics into hot 25.6MB buffer).
// Layer 2 collapses entirely (output is mean over nodes):
//   g = (sum_i h_i)@root2/N + b2 + sum_r (sum_{e in r} h[src_e]*inv[r][dst_e])@W2[r]/N
//   -> only a 576-float reduction needed, no per-node layer-2 output.

#define CH 64

__global__ void count_kernel(const int* __restrict__ dst, const int* __restrict__ etype,
                             float* __restrict__ cnt, int E) {
    int e = blockIdx.x * blockDim.x + threadIdx.x;
    if (e < E) {
        unsafeAtomicAdd(&cnt[dst[e] * 8 + etype[e]], 1.0f);
    }
}

__global__ void recip_kernel(float* __restrict__ cnt, int n) {
    int i = blockIdx.x * blockDim.x + threadIdx.x;
    if (i < n) cnt[i] = 1.0f / fmaxf(cnt[i], 1.0f);
}

// C[M x 64] = A[M x 64] @ B[64 x 64]; EPI==1: C = relu(acc + bias + add)
template <int EPI>
__global__ __launch_bounds__(256) void gemm64_kernel(
    const float* __restrict__ A, const float* __restrict__ B,
    float* __restrict__ C, const float* __restrict__ bias,
    const float* __restrict__ add, int M)
{
    __shared__ float Xs[64][68];  // +4 pad, 16B-aligned rows
    __shared__ float Ws[64][68];
    const int t = threadIdx.x;          // 256 threads
    const int row0 = blockIdx.x * 64;

    for (int f = t * 4; f < 4096; f += 1024) {
        int r = f >> 6, c = f & 63;
        *(float4*)&Ws[r][c] = *(const float4*)&B[f];
        int row = row0 + r;
        float4 v = make_float4(0.f, 0.f, 0.f, 0.f);
        if (row < M) v = *(const float4*)&A[(size_t)row * CH + c];
        *(float4*)&Xs[r][c] = v;
    }
    __syncthreads();

    const int tx = t & 15;   // output group: outs tx*4 .. tx*4+3
    const int ty = t >> 4;   // node group:  rows ty*4 .. ty*4+3
    float acc[4][4] = {};
    #pragma unroll 8
    for (int k = 0; k < 64; ++k) {
        float4 w = *(const float4*)&Ws[k][tx * 4];
        float x0 = Xs[ty * 4 + 0][k];
        float x1 = Xs[ty * 4 + 1][k];
        float x2 = Xs[ty * 4 + 2][k];
        float x3 = Xs[ty * 4 + 3][k];
        acc[0][0] += x0 * w.x; acc[0][1] += x0 * w.y; acc[0][2] += x0 * w.z; acc[0][3] += x0 * w.w;
        acc[1][0] += x1 * w.x; acc[1][1] += x1 * w.y; acc[1][2] += x1 * w.z; acc[1][3] += x1 * w.w;
        acc[2][0] += x2 * w.x; acc[2][1] += x2 * w.y; acc[2][2] += x2 * w.z; acc[2][3] += x2 * w.w;
        acc[3][0] += x3 * w.x; acc[3][1] += x3 * w.y; acc[3][2] += x3 * w.z; acc[3][3] += x3 * w.w;
    }

    #pragma unroll
    for (int a = 0; a < 4; ++a) {
        int row = row0 + ty * 4 + a;
        if (row < M) {
            int o = tx * 4;
            if (EPI == 0) {
                *(float4*)&C[(size_t)row * CH + o] =
                    make_float4(acc[a][0], acc[a][1], acc[a][2], acc[a][3]);
            } else {
                float4 hv = *(const float4*)&add[(size_t)row * CH + o];
                float4 bv = *(const float4*)&bias[o];
                float4 rv;
                rv.x = fmaxf(acc[a][0] + hv.x + bv.x, 0.f);
                rv.y = fmaxf(acc[a][1] + hv.y + bv.y, 0.f);
                rv.z = fmaxf(acc[a][2] + hv.z + bv.z, 0.f);
                rv.w = fmaxf(acc[a][3] + hv.w + bv.w, 0.f);
                *(float4*)&C[(size_t)row * CH + o] = rv;
            }
        }
    }
}

// hmsg[dst] += xt[src] * inv[r][dst]  for edges of relation r. One wave per edge.
__global__ __launch_bounds__(256) void scatter_kernel(
    const int* __restrict__ src, const int* __restrict__ dst, const int* __restrict__ etype,
    const float* __restrict__ xt, const float* __restrict__ inv,
    float* __restrict__ hmsg, int E, int r)
{
    const int lane = threadIdx.x & 63;
    int wave = (blockIdx.x << 2) | (threadIdx.x >> 6);
    const int wstride = gridDim.x << 2;
    for (int e = wave; e < E; e += wstride) {
        if (etype[e] != r) continue;
        int d = dst[e], s = src[e];
        float v = inv[d * 8 + r];
        unsafeAtomicAdd(&hmsg[d * CH + lane], xt[(size_t)s * CH + lane] * v);
    }
}

// s_r[c] = sum over edges of relation r of h[src][c] * inv[r][dst]
__global__ __launch_bounds__(256) void edge_reduce_kernel(
    const int* __restrict__ src, const int* __restrict__ dst, const int* __restrict__ etype,
    const float* __restrict__ h, const float* __restrict__ inv,
    float* __restrict__ sacc, int E)
{
    const int lane = threadIdx.x & 63;
    const int w = threadIdx.x >> 6;
    int wave = (blockIdx.x << 2) | w;
    const int wstride = gridDim.x << 2;
    float racc[8] = {};
    for (int e = wave; e < E; e += wstride) {
        int r = etype[e];
        int d = dst[e], s = src[e];
        float v = h[(size_t)s * CH + lane] * inv[d * 8 + r];
        #pragma unroll
        for (int rr = 0; rr < 8; ++rr)
            racc[rr] += (rr == r) ? v : 0.0f;
    }
    __shared__ float red[4][8][64];
    #pragma unroll
    for (int rr = 0; rr < 8; ++rr) red[w][rr][lane] = racc[rr];
    __syncthreads();
    if (w == 0) {
        #pragma unroll
        for (int rr = 0; rr < 8; ++rr) {
            float s4 = red[0][rr][lane] + red[1][rr][lane] + red[2][rr][lane] + red[3][rr][lane];
            unsafeAtomicAdd(&sacc[rr * 64 + lane], s4);
        }
    }
}

// s0[c] = sum_i h[i][c]
__global__ __launch_bounds__(256) void node_reduce_kernel(
    const float* __restrict__ h, float* __restrict__ s0, int N)
{
    const int lane = threadIdx.x & 63;
    const int w = threadIdx.x >> 6;
    int wave = (blockIdx.x << 2) | w;
    const int wstride = gridDim.x << 2;
    float acc = 0.f;
    for (int i = wave; i < N; i += wstride) acc += h[(size_t)i * CH + lane];
    __shared__ float red[4][64];
    red[w][lane] = acc;
    __syncthreads();
    if (w == 0) {
        float s4 = red[0][lane] + red[1][lane] + red[2][lane] + red[3][lane];
        unsafeAtomicAdd(&s0[lane], s4);
    }
}

// g[o] = (s0@root2 + sum_r s_r@W2[r]) / N + b2;  out = log_softmax(g)
__global__ void finalize_kernel(const float* __restrict__ sacc, const float* __restrict__ root2,
                                const float* __restrict__ W2, const float* __restrict__ b2,
                                float* __restrict__ out, float invN)
{
    __shared__ float g[16];
    int t = threadIdx.x;
    if (t < 16) {
        const float* s0 = sacc + 512;
        float acc = 0.f;
        for (int c = 0; c < 64; ++c) acc += s0[c] * root2[c * 16 + t];
        for (int r = 0; r < 8; ++r) {
            const float* sr = sacc + r * 64;
            for (int c = 0; c < 64; ++c) acc += sr[c] * W2[(r * 64 + c) * 16 + t];
        }
        g[t] = acc * invN + b2[t];
    }
    __syncthreads();
    if (t < 16) {
        float m = -1e30f;
        for (int i = 0; i < 16; ++i) m = fmaxf(m, g[i]);
        float s = 0.f;
        for (int i = 0; i < 16; ++i) s += expf(g[i] - m);
        out[t] = g[t] - (m + logf(s));
    }
}

extern "C" void kernel_launch(void* const* d_in, const int* in_sizes, int n_in,
                              void* d_out, int out_size, void* d_ws, size_t ws_size,
                              hipStream_t stream)
{
    const float* x     = (const float*)d_in[0];
    const int*   eidx  = (const int*)d_in[1];
    const int*   etype = (const int*)d_in[2];
    const float* W1    = (const float*)d_in[3];
    const float* root1 = (const float*)d_in[4];
    const float* b1    = (const float*)d_in[5];
    const float* W2    = (const float*)d_in[6];
    const float* root2 = (const float*)d_in[7];
    const float* b2    = (const float*)d_in[8];
    float* out = (float*)d_out;

    const int E = in_sizes[1] / 2;
    const int N = in_sizes[0] / CH;
    const int* srcI = eidx;
    const int* dstI = eidx + E;

    // workspace layout (floats): [cnt/inv N*8 | hmsg N*64 | sacc 576 | xt N*64 | h N*64]
    float* ws   = (float*)d_ws;
    float* cnt  = ws;
    float* hmsg = cnt + (size_t)N * 8;
    float* sacc = hmsg + (size_t)N * CH;   // s_r: [0,512), s0: [512,576)
    float* xt   = sacc + 576;
    float* h    = xt + (size_t)N * CH;

    // zero cnt + hmsg + sacc (contiguous prefix)
    size_t zero_bytes = ((size_t)N * 8 + (size_t)N * CH + 576) * sizeof(float);
    hipMemsetAsync(d_ws, 0, zero_bytes, stream);

    count_kernel<<<(E + 255) / 256, 256, 0, stream>>>(dstI, etype, cnt, E);
    recip_kernel<<<(N * 8 + 255) / 256, 256, 0, stream>>>(cnt, N * 8);

    const int gBlocks = (N + 63) / 64;
    for (int r = 0; r < 8; ++r) {
        gemm64_kernel<0><<<gBlocks, 256, 0, stream>>>(x, W1 + r * 4096, xt, nullptr, nullptr, N);
        scatter_kernel<<<2048, 256, 0, stream>>>(srcI, dstI, etype, xt, cnt, hmsg, E, r);
    }
    gemm64_kernel<1><<<gBlocks, 256, 0, stream>>>(x, root1, h, b1, hmsg, N);

    edge_reduce_kernel<<<2048, 256, 0, stream>>>(srcI, dstI, etype, h, cnt, sacc, E);
    node_reduce_kernel<<<1024, 256, 0, stream>>>(h, sacc + 512, N);
    finalize_kernel<<<1, 64, 0, stream>>>(sacc, root2, W2, b2, out, 1.0f / (float)N);
}

// Round 3
// 988.971 us; speedup vs baseline: 1.3566x; 1.3566x over previous
//
#include <hip/hip_runtime.h>
#include <hip/hip_bf16.h>

// RGCN 2-layer + global mean pool + log_softmax.
// Round 3: eliminate the 102.4M f32 atomics (was ~950us) via CSR counting
// sort by key = dst*8+rel, then per-relation gather-aggregation (no atomics).
// Layer 2 still collapses to a 576-float reduction.

#define CH 64

// ---- counting sort ----------------------------------------------------------

__global__ void count_kernel(const int* __restrict__ dst, const int* __restrict__ etype,
                             int* __restrict__ cnt, int E) {
    int e = blockIdx.x * blockDim.x + threadIdx.x;
    if (e < E) atomicAdd(&cnt[dst[e] * 8 + etype[e]], 1);
}

__global__ void inv_kernel(const int* __restrict__ cnt, float* __restrict__ inv, int n) {
    int i = blockIdx.x * blockDim.x + threadIdx.x;
    if (i < n) inv[i] = 1.0f / (float)max(cnt[i], 1);
}

// exclusive scan, 1024 items/block. scan1 writes block-local exclusive
// prefixes + per-block totals; scan2 scans totals; scan3 adds offsets and
// mirrors to cursor.
__global__ __launch_bounds__(256) void scan1_kernel(const int* __restrict__ in,
                                                    int* __restrict__ out,
                                                    int* __restrict__ bsum, int n) {
    __shared__ int ts[256];
    int t = threadIdx.x;
    int base = blockIdx.x * 1024 + t * 4;
    int4 v = make_int4(0, 0, 0, 0);
    if (base + 3 < n) v = *(const int4*)&in[base];
    else {
        if (base < n)     v.x = in[base];
        if (base + 1 < n) v.y = in[base + 1];
        if (base + 2 < n) v.z = in[base + 2];
        if (base + 3 < n) v.w = in[base + 3];
    }
    int s = v.x + v.y + v.z + v.w;
    ts[t] = s;
    __syncthreads();
    for (int off = 1; off < 256; off <<= 1) {
        int val = (t >= off) ? ts[t - off] : 0;
        __syncthreads();
        ts[t] += val;
        __syncthreads();
    }
    int excl = ts[t] - s;
    int4 o;
    o.x = excl; o.y = excl + v.x; o.z = excl + v.x + v.y; o.w = excl + v.x + v.y + v.z;
    if (base + 3 < n) *(int4*)&out[base] = o;
    else {
        if (base < n)     out[base] = o.x;
        if (base + 1 < n) out[base + 1] = o.y;
        if (base + 2 < n) out[base + 2] = o.z;
        if (base + 3 < n) out[base + 3] = o.w;
    }
    if (t == 255) bsum[blockIdx.x] = ts[255];
}

__global__ __launch_bounds__(1024) void scan2_kernel(int* __restrict__ bsum, int nb) {
    __shared__ int ts[1024];
    int t = threadIdx.x;
    int v = (t < nb) ? bsum[t] : 0;
    ts[t] = v;
    __syncthreads();
    for (int off = 1; off < 1024; off <<= 1) {
        int val = (t >= off) ? ts[t - off] : 0;
        __syncthreads();
        ts[t] += val;
        __syncthreads();
    }
    if (t < nb) bsum[t] = ts[t] - v;  // exclusive
}

__global__ __launch_bounds__(256) void scan3_kernel(int* __restrict__ rowptr,
                                                    int* __restrict__ cursor,
                                                    const int* __restrict__ bsum,
                                                    int n, int total) {
    int t = threadIdx.x;
    int base = blockIdx.x * 1024 + t * 4;
    int add = bsum[blockIdx.x];
    #pragma unroll
    for (int k = 0; k < 4; ++k) {
        int i = base + k;
        if (i < n) {
            int v = rowptr[i] + add;
            rowptr[i] = v;
            cursor[i] = v;
        }
    }
    if (blockIdx.x == 0 && t == 0) rowptr[n] = total;
}

__global__ void place_kernel(const int* __restrict__ src, const int* __restrict__ dst,
                             const int* __restrict__ etype, int* __restrict__ cursor,
                             int* __restrict__ perm, int E) {
    int e = blockIdx.x * blockDim.x + threadIdx.x;
    if (e < E) {
        int key = dst[e] * 8 + etype[e];
        int pos = atomicAdd(&cursor[key], 1);
        perm[pos] = src[e];
    }
}

// ---- GEMMs ------------------------------------------------------------------

// C[M x 64] = A[M x 64] @ B[64 x 64]; EPI==1: C = relu(acc + bias + add)
template <int EPI>
__global__ __launch_bounds__(256) void gemm64_kernel(
    const float* __restrict__ A, const float* __restrict__ B,
    float* __restrict__ C, const float* __restrict__ bias,
    const float* __restrict__ add, int M)
{
    __shared__ float Xs[64][68];
    __shared__ float Ws[64][68];
    const int t = threadIdx.x;
    const int row0 = blockIdx.x * 64;

    for (int f = t * 4; f < 4096; f += 1024) {
        int r = f >> 6, c = f & 63;
        *(float4*)&Ws[r][c] = *(const float4*)&B[f];
        int row = row0 + r;
        float4 v = make_float4(0.f, 0.f, 0.f, 0.f);
        if (row < M) v = *(const float4*)&A[(size_t)row * CH + c];
        *(float4*)&Xs[r][c] = v;
    }
    __syncthreads();

    const int tx = t & 15;
    const int ty = t >> 4;
    float acc[4][4] = {};
    #pragma unroll 8
    for (int k = 0; k < 64; ++k) {
        float4 w = *(const float4*)&Ws[k][tx * 4];
        float x0 = Xs[ty * 4 + 0][k];
        float x1 = Xs[ty * 4 + 1][k];
        float x2 = Xs[ty * 4 + 2][k];
        float x3 = Xs[ty * 4 + 3][k];
        acc[0][0] += x0 * w.x; acc[0][1] += x0 * w.y; acc[0][2] += x0 * w.z; acc[0][3] += x0 * w.w;
        acc[1][0] += x1 * w.x; acc[1][1] += x1 * w.y; acc[1][2] += x1 * w.z; acc[1][3] += x1 * w.w;
        acc[2][0] += x2 * w.x; acc[2][1] += x2 * w.y; acc[2][2] += x2 * w.z; acc[2][3] += x2 * w.w;
        acc[3][0] += x3 * w.x; acc[3][1] += x3 * w.y; acc[3][2] += x3 * w.z; acc[3][3] += x3 * w.w;
    }

    #pragma unroll
    for (int a = 0; a < 4; ++a) {
        int row = row0 + ty * 4 + a;
        if (row < M) {
            int o = tx * 4;
            if (EPI == 0) {
                *(float4*)&C[(size_t)row * CH + o] =
                    make_float4(acc[a][0], acc[a][1], acc[a][2], acc[a][3]);
            } else {
                float4 hv = *(const float4*)&add[(size_t)row * CH + o];
                float4 bv = *(const float4*)&bias[o];
                float4 rv;
                rv.x = fmaxf(acc[a][0] + hv.x + bv.x, 0.f);
                rv.y = fmaxf(acc[a][1] + hv.y + bv.y, 0.f);
                rv.z = fmaxf(acc[a][2] + hv.z + bv.z, 0.f);
                rv.w = fmaxf(acc[a][3] + hv.w + bv.w, 0.f);
                *(float4*)&C[(size_t)row * CH + o] = rv;
            }
        }
    }
}

// ---- per-relation gather aggregation (no atomics) ---------------------------
// wave per node i: hmsg[i] (+)= inv[i*8+r] * sum_{j in seg(i,r)} xt[perm[j]]

__global__ __launch_bounds__(256) void agg_kernel(
    const int* __restrict__ rowptr, const int* __restrict__ perm,
    const float* __restrict__ inv, const float* __restrict__ xt,
    float* __restrict__ hmsg, int N, int r, int first)
{
    const int lane = threadIdx.x & 63;
    const int i = (blockIdx.x << 2) | (threadIdx.x >> 6);  // node = global wave id
    if (i >= N) return;
    const int key = i * 8 + r;
    const int base = rowptr[key];
    const int end = rowptr[key + 1];
    float acc = 0.f;
    for (int j = base; j < end; ++j) {
        int s = perm[j];
        acc += xt[(size_t)s * CH + lane];
    }
    acc *= inv[key];
    float* p = &hmsg[(size_t)i * CH + lane];
    if (first) *p = acc;
    else       *p += acc;
}

// ---- layer-2 collapse -------------------------------------------------------

__global__ __launch_bounds__(256) void edge_reduce_kernel(
    const int* __restrict__ src, const int* __restrict__ dst, const int* __restrict__ etype,
    const float* __restrict__ h, const float* __restrict__ inv,
    float* __restrict__ sacc, int E)
{
    const int lane = threadIdx.x & 63;
    const int w = threadIdx.x >> 6;
    int wave = (blockIdx.x << 2) | w;
    const int wstride = gridDim.x << 2;
    float racc[8] = {};
    for (int e = wave; e < E; e += wstride) {
        int r = etype[e];
        int d = dst[e], s = src[e];
        float v = h[(size_t)s * CH + lane] * inv[d * 8 + r];
        #pragma unroll
        for (int rr = 0; rr < 8; ++rr)
            racc[rr] += (rr == r) ? v : 0.0f;
    }
    __shared__ float red[4][8][64];
    #pragma unroll
    for (int rr = 0; rr < 8; ++rr) red[w][rr][lane] = racc[rr];
    __syncthreads();
    if (w == 0) {
        #pragma unroll
        for (int rr = 0; rr < 8; ++rr) {
            float s4 = red[0][rr][lane] + red[1][rr][lane] + red[2][rr][lane] + red[3][rr][lane];
            unsafeAtomicAdd(&sacc[rr * 64 + lane], s4);
        }
    }
}

__global__ __launch_bounds__(256) void node_reduce_kernel(
    const float* __restrict__ h, float* __restrict__ s0, int N)
{
    const int lane = threadIdx.x & 63;
    const int w = threadIdx.x >> 6;
    int wave = (blockIdx.x << 2) | w;
    const int wstride = gridDim.x << 2;
    float acc = 0.f;
    for (int i = wave; i < N; i += wstride) acc += h[(size_t)i * CH + lane];
    __shared__ float red[4][64];
    red[w][lane] = acc;
    __syncthreads();
    if (w == 0) {
        float s4 = red[0][lane] + red[1][lane] + red[2][lane] + red[3][lane];
        unsafeAtomicAdd(&s0[lane], s4);
    }
}

__global__ void finalize_kernel(const float* __restrict__ sacc, const float* __restrict__ root2,
                                const float* __restrict__ W2, const float* __restrict__ b2,
                                float* __restrict__ out, float invN)
{
    __shared__ float g[16];
    int t = threadIdx.x;
    if (t < 16) {
        const float* s0 = sacc + 512;
        float acc = 0.f;
        for (int c = 0; c < 64; ++c) acc += s0[c] * root2[c * 16 + t];
        for (int r = 0; r < 8; ++r) {
            const float* sr = sacc + r * 64;
            for (int c = 0; c < 64; ++c) acc += sr[c] * W2[(r * 64 + c) * 16 + t];
        }
        g[t] = acc * invN + b2[t];
    }
    __syncthreads();
    if (t < 16) {
        float m = -1e30f;
        for (int i = 0; i < 16; ++i) m = fmaxf(m, g[i]);
        float s = 0.f;
        for (int i = 0; i < 16; ++i) s += expf(g[i] - m);
        out[t] = g[t] - (m + logf(s));
    }
}

// ---- launch -----------------------------------------------------------------

extern "C" void kernel_launch(void* const* d_in, const int* in_sizes, int n_in,
                              void* d_out, int out_size, void* d_ws, size_t ws_size,
                              hipStream_t stream)
{
    const float* x     = (const float*)d_in[0];
    const int*   eidx  = (const int*)d_in[1];
    const int*   etype = (const int*)d_in[2];
    const float* W1    = (const float*)d_in[3];
    const float* root1 = (const float*)d_in[4];
    const float* b1    = (const float*)d_in[5];
    const float* W2    = (const float*)d_in[6];
    const float* root2 = (const float*)d_in[7];
    const float* b2    = (const float*)d_in[8];
    float* out = (float*)d_out;

    const int E = in_sizes[1] / 2;
    const int N = in_sizes[0] / CH;
    const int NKEY = N * 8;
    const int* srcI = eidx;
    const int* dstI = eidx + E;

    // workspace layout (4B elements):
    // [cnt NKEY | sacc 576 | inv NKEY | rowptr NKEY+1 | cursor NKEY | bsum 1024
    //  | perm E | (pad to 4) xt N*64 | hmsg N*64 | h N*64 ]
    char* wsb = (char*)d_ws;
    int*   cnt    = (int*)wsb;
    float* sacc   = (float*)(cnt + NKEY);          // s_r [0,512), s0 [512,576)
    float* inv    = (float*)(sacc + 576);
    int*   rowptr = (int*)(inv + NKEY);            // NKEY+1
    int*   cursor = rowptr + NKEY + 1;
    int*   bsum   = cursor + NKEY;                 // 1024
    int*   perm   = bsum + 1024;                   // E
    size_t off    = (size_t)(perm + E - (int*)wsb);
    off = (off + 3) & ~(size_t)3;                  // 16B-align
    float* xt   = (float*)wsb + off;
    float* hmsg = xt + (size_t)N * CH;
    float* h    = hmsg + (size_t)N * CH;

    // zero the histogram + sacc (contiguous prefix)
    hipMemsetAsync(d_ws, 0, (size_t)(NKEY + 576) * 4, stream);

    count_kernel<<<(E + 255) / 256, 256, 0, stream>>>(dstI, etype, cnt, E);
    inv_kernel<<<(NKEY + 255) / 256, 256, 0, stream>>>(cnt, inv, NKEY);

    const int NB1 = (NKEY + 1023) / 1024;          // 782 for N=100K (must be <=1024)
    scan1_kernel<<<NB1, 256, 0, stream>>>(cnt, rowptr, bsum, NKEY);
    scan2_kernel<<<1, 1024, 0, stream>>>(bsum, NB1);
    scan3_kernel<<<NB1, 256, 0, stream>>>(rowptr, cursor, bsum, NKEY, E);
    place_kernel<<<(E + 255) / 256, 256, 0, stream>>>(srcI, dstI, etype, cursor, perm, E);

    const int gBlocks = (N + 63) / 64;
    const int aBlocks = (N + 3) / 4;
    for (int r = 0; r < 8; ++r) {
        gemm64_kernel<0><<<gBlocks, 256, 0, stream>>>(x, W1 + r * 4096, xt, nullptr, nullptr, N);
        agg_kernel<<<aBlocks, 256, 0, stream>>>(rowptr, perm, inv, xt, hmsg, N, r, r == 0);
    }
    gemm64_kernel<1><<<gBlocks, 256, 0, stream>>>(x, root1, h, b1, hmsg, N);

    edge_reduce_kernel<<<2048, 256, 0, stream>>>(srcI, dstI, etype, h, inv, sacc, E);
    node_reduce_kernel<<<1024, 256, 0, stream>>>(h, sacc + 512, N);
    finalize_kernel<<<1, 64, 0, stream>>>(sacc, root2, W2, b2, out, 1.0f / (float)N);
}

// Round 4
// 752.422 us; speedup vs baseline: 1.7831x; 1.3144x over previous
//
#include <hip/hip_runtime.h>
#include <hip/hip_bf16.h>

// RGCN 2-layer + global mean pool + log_softmax. Round 4.
// Layer 1: single fused kernel. One wave per 16-node tile: per (node,rel) CSR
//   segment gather bf16 x rows -> fp32 agg -> scale by 1/deg -> pack to LDS in
//   MFMA A-layout -> mfma_f32_16x16x32_bf16 with pre-swizzled W frags.
//   root1 = 9th "relation" with agg = x[i].
// Layer 2: collapses to s_r = sum_s h[s]*kappa[s][r], kappa from graph only.

#define CH 64

typedef __attribute__((ext_vector_type(8))) short short8;
typedef __attribute__((ext_vector_type(4))) float f32x4;

__device__ inline ushort f2bf(float f) {
    unsigned b = __float_as_uint(f);
    unsigned r = (b + 0x7FFFu + ((b >> 16) & 1u)) >> 16;
    return (ushort)r;
}
__device__ inline float bf2f(ushort u) {
    return __uint_as_float(((unsigned)u) << 16);
}

// ---- preprocessing ----------------------------------------------------------

__global__ void count_kernel(const int* __restrict__ dst, const int* __restrict__ etype,
                             int* __restrict__ cnt, int E) {
    int e = blockIdx.x * blockDim.x + threadIdx.x;
    if (e < E) atomicAdd(&cnt[dst[e] * 8 + etype[e]], 1);
}

__global__ void inv_kernel(const int* __restrict__ cnt, float* __restrict__ inv, int n) {
    int i = blockIdx.x * blockDim.x + threadIdx.x;
    if (i < n) inv[i] = 1.0f / (float)max(cnt[i], 1);
}

__global__ __launch_bounds__(256) void scan1_kernel(const int* __restrict__ in,
                                                    int* __restrict__ out,
                                                    int* __restrict__ bsum, int n) {
    __shared__ int ts[256];
    int t = threadIdx.x;
    int base = blockIdx.x * 1024 + t * 4;
    int4 v = make_int4(0, 0, 0, 0);
    if (base + 3 < n) v = *(const int4*)&in[base];
    else {
        if (base < n)     v.x = in[base];
        if (base + 1 < n) v.y = in[base + 1];
        if (base + 2 < n) v.z = in[base + 2];
        if (base + 3 < n) v.w = in[base + 3];
    }
    int s = v.x + v.y + v.z + v.w;
    ts[t] = s;
    __syncthreads();
    for (int off = 1; off < 256; off <<= 1) {
        int val = (t >= off) ? ts[t - off] : 0;
        __syncthreads();
        ts[t] += val;
        __syncthreads();
    }
    int excl = ts[t] - s;
    int4 o;
    o.x = excl; o.y = excl + v.x; o.z = excl + v.x + v.y; o.w = excl + v.x + v.y + v.z;
    if (base + 3 < n) *(int4*)&out[base] = o;
    else {
        if (base < n)     out[base] = o.x;
        if (base + 1 < n) out[base + 1] = o.y;
        if (base + 2 < n) out[base + 2] = o.z;
        if (base + 3 < n) out[base + 3] = o.w;
    }
    if (t == 255) bsum[blockIdx.x] = ts[255];
}

__global__ __launch_bounds__(1024) void scan2_kernel(int* __restrict__ bsum, int nb) {
    __shared__ int ts[1024];
    int t = threadIdx.x;
    int v = (t < nb) ? bsum[t] : 0;
    ts[t] = v;
    __syncthreads();
    for (int off = 1; off < 1024; off <<= 1) {
        int val = (t >= off) ? ts[t - off] : 0;
        __syncthreads();
        ts[t] += val;
        __syncthreads();
    }
    if (t < nb) bsum[t] = ts[t] - v;  // exclusive
}

__global__ __launch_bounds__(256) void scan3_kernel(int* __restrict__ rowptr,
                                                    int* __restrict__ cursor,
                                                    const int* __restrict__ bsum,
                                                    int n, int total) {
    int t = threadIdx.x;
    int base = blockIdx.x * 1024 + t * 4;
    int add = bsum[blockIdx.x];
    #pragma unroll
    for (int k = 0; k < 4; ++k) {
        int i = base + k;
        if (i < n) {
            int v = rowptr[i] + add;
            rowptr[i] = v;
            cursor[i] = v;
        }
    }
    if (blockIdx.x == 0 && t == 0) rowptr[n] = total;
}

__global__ void place_kernel(const int* __restrict__ src, const int* __restrict__ dst,
                             const int* __restrict__ etype, int* __restrict__ cursor,
                             int* __restrict__ perm, int E) {
    int e = blockIdx.x * blockDim.x + threadIdx.x;
    if (e < E) {
        int key = dst[e] * 8 + etype[e];
        int pos = atomicAdd(&cursor[key], 1);
        perm[pos] = src[e];
    }
}

// kappa[s][r] = sum_{e: src=s, rel=r} inv[dst_e*8+r]   (graph-only quantity)
__global__ void kappa_kernel(const int* __restrict__ src, const int* __restrict__ dst,
                             const int* __restrict__ etype, const float* __restrict__ inv,
                             float* __restrict__ kappa, int E) {
    int e = blockIdx.x * blockDim.x + threadIdx.x;
    if (e < E) {
        int r = etype[e];
        unsafeAtomicAdd(&kappa[src[e] * 8 + r], inv[dst[e] * 8 + r]);
    }
}

// bf16 copy of x
__global__ void xbf_kernel(const float* __restrict__ x, ushort* __restrict__ xbf, int n4) {
    int i = blockIdx.x * blockDim.x + threadIdx.x;
    if (i < n4) {
        float4 v = ((const float4*)x)[i];
        ushort4 o = make_ushort4(f2bf(v.x), f2bf(v.y), f2bf(v.z), f2bf(v.w));
        ((ushort4*)xbf)[i] = o;
    }
}

// pre-swizzle 9 weight matrices (W1[0..7], root1) into bf16 B-fragment layout:
// wf[(((rel*2+ks)*4+ct)*64+lane)*8+j] = W[rel][k=ks*32+(lane>>4)*8+j][n=ct*16+(lane&15)]
__global__ void wfrag_kernel(const float* __restrict__ W1, const float* __restrict__ root1,
                             ushort* __restrict__ wf) {
    int idx = blockIdx.x * blockDim.x + threadIdx.x;
    if (idx >= 9 * 2 * 4 * 64 * 8) return;
    int j    = idx & 7;
    int lane = (idx >> 3) & 63;
    int ct   = (idx >> 9) & 3;
    int ks   = (idx >> 11) & 1;
    int rel  = idx >> 12;
    int k = ks * 32 + (lane >> 4) * 8 + j;
    int n = ct * 16 + (lane & 15);
    float v = (rel < 8) ? W1[((size_t)rel * 64 + k) * 64 + n] : root1[(size_t)k * 64 + n];
    wf[idx] = f2bf(v);
}

// ---- fused layer 1 ----------------------------------------------------------
// one wave per 16-node tile; h[i] = relu(b1 + x[i]@root1 + sum_r inv*seg_sum@W1[r])

__global__ __launch_bounds__(256) void rgcn1_fused_kernel(
    const int* __restrict__ rowptr, const int* __restrict__ perm,
    const float* __restrict__ inv, const ushort* __restrict__ xbf,
    const ushort* __restrict__ wfrag, const float* __restrict__ b1,
    float* __restrict__ h, int N, int NKEY)
{
    __shared__ ushort Abuf[4][16 * 72];  // per-wave 16x64 bf16, row stride 72 (bank-safe, 16B-aligned)
    const int widx = threadIdx.x >> 6;
    const int lane = threadIdx.x & 63;
    const int wid = (blockIdx.x << 2) | widx;
    const int base = wid << 4;
    if (base >= N) return;
    const int m0 = lane & 15;
    const int q = lane >> 4;
    ushort* ab = Abuf[widx];

    const int key0 = base * 8;
    int r0v = rowptr[min(key0 + lane, NKEY)];
    int r1v = rowptr[min(key0 + 64 + lane, NKEY)];
    int r2v = rowptr[min(key0 + 128, NKEY)];
    float iv0 = inv[min(key0 + lane, NKEY - 1)];
    float iv1 = inv[min(key0 + 64 + lane, NKEY - 1)];

    f32x4 acc4[4];
    #pragma unroll
    for (int ct = 0; ct < 4; ++ct) acc4[ct] = (f32x4)(0.0f);

    for (int r = 0; r < 9; ++r) {
        #pragma unroll
        for (int m = 0; m < 16; ++m) {
            float a = 0.f;
            bool valid = (base + m) < N;
            if (r < 8) {
                if (valid) {
                    int kk = m * 8 + r;
                    int st = (kk < 64) ? __shfl(r0v, kk) : __shfl(r1v, kk - 64);
                    int en = (kk + 1 < 64) ? __shfl(r0v, kk + 1)
                            : ((kk + 1 < 128) ? __shfl(r1v, kk + 1 - 64) : r2v);
                    for (int j = st; j < en; ++j) {
                        int s = perm[j];
                        a += bf2f(xbf[(size_t)s * CH + lane]);
                    }
                    float iv = (kk < 64) ? __shfl(iv0, kk) : __shfl(iv1, kk - 64);
                    a *= iv;
                }
            } else {
                if (valid) a = bf2f(xbf[(size_t)(base + m) * CH + lane]);
            }
            ab[m * 72 + lane] = f2bf(a);
        }
        // 2 K-steps x 4 col-tiles of 16x16x32 MFMA
        #pragma unroll
        for (int s = 0; s < 2; ++s) {
            short8 av = *(short8*)&ab[m0 * 72 + s * 32 + q * 8];
            #pragma unroll
            for (int ct = 0; ct < 4; ++ct) {
                short8 bv = *(const short8*)&wfrag[(((size_t)(r * 2 + s) * 4 + ct) * 64 + lane) * 8];
                acc4[ct] = __builtin_amdgcn_mfma_f32_16x16x32_bf16(av, bv, acc4[ct], 0, 0, 0);
            }
        }
    }

    // epilogue: D[row=q*4+v][col=ct*16+m0]; row = node-in-tile
    #pragma unroll
    for (int ct = 0; ct < 4; ++ct) {
        int c = ct * 16 + m0;
        float bb = b1[c];
        #pragma unroll
        for (int v = 0; v < 4; ++v) {
            int node = base + q * 4 + v;
            if (node < N)
                h[(size_t)node * CH + c] = fmaxf(acc4[ct][v] + bb, 0.f);
        }
    }
}

// ---- layer-2 collapse: s_r[c] = sum_i h[i][c]*kappa[i][r], s0 = sum_i h[i] --

__global__ __launch_bounds__(256) void kred_kernel(
    const float* __restrict__ h, const float* __restrict__ kappa,
    float* __restrict__ sacc, int N)
{
    const int lane = threadIdx.x & 63;
    const int w = threadIdx.x >> 6;
    int wave = (blockIdx.x << 2) | w;
    const int wstride = gridDim.x << 2;
    float racc[9] = {};
    for (int i = wave; i < N; i += wstride) {
        float hv = h[(size_t)i * CH + lane];
        #pragma unroll
        for (int r = 0; r < 8; ++r) racc[r] += hv * kappa[i * 8 + r];
        racc[8] += hv;
    }
    __shared__ float red[4][9][64];
    #pragma unroll
    for (int r = 0; r < 9; ++r) red[w][r][lane] = racc[r];
    __syncthreads();
    if (w == 0) {
        #pragma unroll
        for (int r = 0; r < 9; ++r) {
            float s4 = red[0][r][lane] + red[1][r][lane] + red[2][r][lane] + red[3][r][lane];
            unsafeAtomicAdd(&sacc[r * 64 + lane], s4);
        }
    }
}

// g[o] = (s0@root2 + sum_r s_r@W2[r]) / N + b2;  out = log_softmax(g)
__global__ void finalize_kernel(const float* __restrict__ sacc, const float* __restrict__ root2,
                                const float* __restrict__ W2, const float* __restrict__ b2,
                                float* __restrict__ out, float invN)
{
    __shared__ float g[16];
    int t = threadIdx.x;
    if (t < 16) {
        const float* s0 = sacc + 512;
        float acc = 0.f;
        for (int c = 0; c < 64; ++c) acc += s0[c] * root2[c * 16 + t];
        for (int r = 0; r < 8; ++r) {
            const float* sr = sacc + r * 64;
            for (int c = 0; c < 64; ++c) acc += sr[c] * W2[(r * 64 + c) * 16 + t];
        }
        g[t] = acc * invN + b2[t];
    }
    __syncthreads();
    if (t < 16) {
        float m = -1e30f;
        for (int i = 0; i < 16; ++i) m = fmaxf(m, g[i]);
        float s = 0.f;
        for (int i = 0; i < 16; ++i) s += expf(g[i] - m);
        out[t] = g[t] - (m + logf(s));
    }
}

// ---- launch -----------------------------------------------------------------

extern "C" void kernel_launch(void* const* d_in, const int* in_sizes, int n_in,
                              void* d_out, int out_size, void* d_ws, size_t ws_size,
                              hipStream_t stream)
{
    const float* x     = (const float*)d_in[0];
    const int*   eidx  = (const int*)d_in[1];
    const int*   etype = (const int*)d_in[2];
    const float* W1    = (const float*)d_in[3];
    const float* root1 = (const float*)d_in[4];
    const float* b1    = (const float*)d_in[5];
    const float* W2    = (const float*)d_in[6];
    const float* root2 = (const float*)d_in[7];
    const float* b2    = (const float*)d_in[8];
    float* out = (float*)d_out;

    const int E = in_sizes[1] / 2;
    const int N = in_sizes[0] / CH;
    const int NKEY = N * 8;
    const int* srcI = eidx;
    const int* dstI = eidx + E;

    // workspace layout (4B units):
    // [cnt NKEY | sacc 576 | kappa NKEY | inv NKEY | rowptr NKEY+1 | cursor NKEY
    //  | bsum 1024 | perm E | pad | xbf N*CH/2 | wfrag 18432 | h N*CH]
    int* wsi = (int*)d_ws;
    int*   cnt    = wsi;
    float* sacc   = (float*)(cnt + NKEY);          // s_r [0,512), s0 [512,576)
    float* kappa  = (float*)(sacc + 576);
    float* inv    = kappa + NKEY;
    int*   rowptr = (int*)(inv + NKEY);            // NKEY+1
    int*   cursor = rowptr + NKEY + 1;
    int*   bsum   = cursor + NKEY;
    int*   perm   = bsum + 1024;
    size_t off = (size_t)((perm + E) - wsi);
    off = (off + 7) & ~(size_t)7;                  // 32B-align
    ushort* xbf  = (ushort*)(wsi + off);           // N*CH ushorts
    ushort* wfg  = xbf + (size_t)N * CH;           // 36864 ushorts (16B-aligned)
    float*  h    = (float*)(wfg + 36864);

    // zero cnt + sacc + kappa (contiguous prefix)
    hipMemsetAsync(d_ws, 0, (size_t)(NKEY + 576 + NKEY) * 4, stream);

    count_kernel<<<(E + 255) / 256, 256, 0, stream>>>(dstI, etype, cnt, E);
    inv_kernel<<<(NKEY + 255) / 256, 256, 0, stream>>>(cnt, inv, NKEY);

    const int NB1 = (NKEY + 1023) / 1024;
    scan1_kernel<<<NB1, 256, 0, stream>>>(cnt, rowptr, bsum, NKEY);
    scan2_kernel<<<1, 1024, 0, stream>>>(bsum, NB1);
    scan3_kernel<<<NB1, 256, 0, stream>>>(rowptr, cursor, bsum, NKEY, E);
    place_kernel<<<(E + 255) / 256, 256, 0, stream>>>(srcI, dstI, etype, cursor, perm, E);
    kappa_kernel<<<(E + 255) / 256, 256, 0, stream>>>(srcI, dstI, etype, inv, kappa, E);

    xbf_kernel<<<((N * CH / 4) + 255) / 256, 256, 0, stream>>>(x, xbf, N * CH / 4);
    wfrag_kernel<<<(36864 + 255) / 256, 256, 0, stream>>>(W1, root1, wfg);

    const int tiles = (N + 15) / 16;
    rgcn1_fused_kernel<<<(tiles + 3) / 4, 256, 0, stream>>>(
        rowptr, perm, inv, xbf, wfg, b1, h, N, NKEY);

    kred_kernel<<<1024, 256, 0, stream>>>(h, kappa, sacc, N);
    finalize_kernel<<<1, 64, 0, stream>>>(sacc, root2, W2, b2, out, 1.0f / (float)N);
}

// Round 5
// 495.303 us; speedup vs baseline: 2.7087x; 1.5191x over previous
//
#include <hip/hip_runtime.h>
#include <hip/hip_bf16.h>

// RGCN 2-layer + global mean pool + log_softmax. Round 5.
// Fused layer-1 gather restructured for MLP: lane = (seg 8) x (chan-grp 8),
// one dwordx4 covers 8 edges' bf16 rows; perm prefetch pipelined.
// kappa folded into place_kernel. Layer 2 collapses via kappa as before.

#define CH 64

typedef __attribute__((ext_vector_type(8))) short short8;
typedef __attribute__((ext_vector_type(4))) float f32x4;

__device__ inline ushort f2bf(float f) {
    unsigned b = __float_as_uint(f);
    unsigned r = (b + 0x7FFFu + ((b >> 16) & 1u)) >> 16;
    return (ushort)r;
}
__device__ inline float bf2f(ushort u) {
    return __uint_as_float(((unsigned)u) << 16);
}

// ---- preprocessing ----------------------------------------------------------

__global__ void count_kernel(const int* __restrict__ dst, const int* __restrict__ etype,
                             int* __restrict__ cnt, int E) {
    int e = blockIdx.x * blockDim.x + threadIdx.x;
    if (e < E) atomicAdd(&cnt[dst[e] * 8 + etype[e]], 1);
}

__global__ void inv_kernel(const int* __restrict__ cnt, float* __restrict__ inv, int n) {
    int i = blockIdx.x * blockDim.x + threadIdx.x;
    if (i < n) inv[i] = 1.0f / (float)max(cnt[i], 1);
}

__global__ __launch_bounds__(256) void scan1_kernel(const int* __restrict__ in,
                                                    int* __restrict__ out,
                                                    int* __restrict__ bsum, int n) {
    __shared__ int ts[256];
    int t = threadIdx.x;
    int base = blockIdx.x * 1024 + t * 4;
    int4 v = make_int4(0, 0, 0, 0);
    if (base + 3 < n) v = *(const int4*)&in[base];
    else {
        if (base < n)     v.x = in[base];
        if (base + 1 < n) v.y = in[base + 1];
        if (base + 2 < n) v.z = in[base + 2];
        if (base + 3 < n) v.w = in[base + 3];
    }
    int s = v.x + v.y + v.z + v.w;
    ts[t] = s;
    __syncthreads();
    for (int off = 1; off < 256; off <<= 1) {
        int val = (t >= off) ? ts[t - off] : 0;
        __syncthreads();
        ts[t] += val;
        __syncthreads();
    }
    int excl = ts[t] - s;
    int4 o;
    o.x = excl; o.y = excl + v.x; o.z = excl + v.x + v.y; o.w = excl + v.x + v.y + v.z;
    if (base + 3 < n) *(int4*)&out[base] = o;
    else {
        if (base < n)     out[base] = o.x;
        if (base + 1 < n) out[base + 1] = o.y;
        if (base + 2 < n) out[base + 2] = o.z;
        if (base + 3 < n) out[base + 3] = o.w;
    }
    if (t == 255) bsum[blockIdx.x] = ts[255];
}

__global__ __launch_bounds__(1024) void scan2_kernel(int* __restrict__ bsum, int nb) {
    __shared__ int ts[1024];
    int t = threadIdx.x;
    int v = (t < nb) ? bsum[t] : 0;
    ts[t] = v;
    __syncthreads();
    for (int off = 1; off < 1024; off <<= 1) {
        int val = (t >= off) ? ts[t - off] : 0;
        __syncthreads();
        ts[t] += val;
        __syncthreads();
    }
    if (t < nb) bsum[t] = ts[t] - v;  // exclusive
}

__global__ __launch_bounds__(256) void scan3_kernel(int* __restrict__ rowptr,
                                                    int* __restrict__ cursor,
                                                    const int* __restrict__ bsum,
                                                    int n, int total) {
    int t = threadIdx.x;
    int base = blockIdx.x * 1024 + t * 4;
    int add = bsum[blockIdx.x];
    #pragma unroll
    for (int k = 0; k < 4; ++k) {
        int i = base + k;
        if (i < n) {
            int v = rowptr[i] + add;
            rowptr[i] = v;
            cursor[i] = v;
        }
    }
    if (blockIdx.x == 0 && t == 0) rowptr[n] = total;
}

// place + kappa in one edge pass:
// perm[pos++] = src;  kappa[src*8+r] += inv[dst*8+r]
__global__ void place_kernel(const int* __restrict__ src, const int* __restrict__ dst,
                             const int* __restrict__ etype, int* __restrict__ cursor,
                             const float* __restrict__ inv, float* __restrict__ kappa,
                             int* __restrict__ perm, int E) {
    int e = blockIdx.x * blockDim.x + threadIdx.x;
    if (e < E) {
        int r = etype[e];
        int s = src[e];
        int key = dst[e] * 8 + r;
        int pos = atomicAdd(&cursor[key], 1);
        perm[pos] = s;
        unsafeAtomicAdd(&kappa[s * 8 + r], inv[key]);
    }
}

// bf16 copy of x
__global__ void xbf_kernel(const float* __restrict__ x, ushort* __restrict__ xbf, int n4) {
    int i = blockIdx.x * blockDim.x + threadIdx.x;
    if (i < n4) {
        float4 v = ((const float4*)x)[i];
        ushort4 o = make_ushort4(f2bf(v.x), f2bf(v.y), f2bf(v.z), f2bf(v.w));
        ((ushort4*)xbf)[i] = o;
    }
}

// pre-swizzle 9 weight matrices (W1[0..7], root1) into bf16 B-fragment layout:
// wf[(((rel*2+ks)*4+ct)*64+lane)*8+j] = W[rel][k=ks*32+(lane>>4)*8+j][n=ct*16+(lane&15)]
__global__ void wfrag_kernel(const float* __restrict__ W1, const float* __restrict__ root1,
                             ushort* __restrict__ wf) {
    int idx = blockIdx.x * blockDim.x + threadIdx.x;
    if (idx >= 9 * 2 * 4 * 64 * 8) return;
    int j    = idx & 7;
    int lane = (idx >> 3) & 63;
    int ct   = (idx >> 9) & 3;
    int ks   = (idx >> 11) & 1;
    int rel  = idx >> 12;
    int k = ks * 32 + (lane >> 4) * 8 + j;
    int n = ct * 16 + (lane & 15);
    float v = (rel < 8) ? W1[((size_t)rel * 64 + k) * 64 + n] : root1[(size_t)k * 64 + n];
    wf[idx] = f2bf(v);
}

// ---- fused layer 1 ----------------------------------------------------------
// one wave per 16-node tile. Gather phase: lane = (sg 8 segs) x (cg 8 chan-grps);
// each lane accumulates 8 channels of one (node,rel) segment; one dwordx4 row
// fragment load covers 8 edges concurrently. Then MFMA vs pre-swizzled W frags.

__global__ __launch_bounds__(256) void rgcn1_fused_kernel(
    const int* __restrict__ rowptr, const int* __restrict__ perm,
    const float* __restrict__ inv, const ushort* __restrict__ xbf,
    const ushort* __restrict__ wfrag, const float* __restrict__ b1,
    float* __restrict__ h, int N, int NKEY)
{
    __shared__ ushort Abuf[4][16 * 72];   // 16x64 bf16 A-tile, row stride 72 (144B)
    __shared__ int    rpS[4][132];        // rowptr[key0 .. key0+128]
    __shared__ float  invS[4][128];
    const int widx = threadIdx.x >> 6;
    const int lane = threadIdx.x & 63;
    const int wid = (blockIdx.x << 2) | widx;
    const int base = wid << 4;
    if (base >= N) return;

    const int m0 = lane & 15;     // MFMA A row / output row group
    const int q  = lane >> 4;     // MFMA quad
    const int sg = lane >> 3;     // segment within group of 8
    const int cg = lane & 7;      // channel group (8 channels)
    ushort* ab = Abuf[widx];
    int*    rpL = rpS[widx];
    float*  ivL = invS[widx];

    const int key0 = base * 8;
    rpL[lane]      = rowptr[min(key0 + lane, NKEY)];
    rpL[64 + lane] = rowptr[min(key0 + 64 + lane, NKEY)];
    if (lane == 0) rpL[128] = rowptr[min(key0 + 128, NKEY)];
    ivL[lane]      = inv[min(key0 + lane, NKEY - 1)];
    ivL[64 + lane] = inv[min(key0 + 64 + lane, NKEY - 1)];

    f32x4 acc4[4];
    #pragma unroll
    for (int ct = 0; ct < 4; ++ct) acc4[ct] = (f32x4)(0.0f);

    for (int r = 0; r < 9; ++r) {
        if (r < 8) {
            // gather phase: 2 halves of 8 segments each
            #pragma unroll
            for (int ss = 0; ss < 2; ++ss) {
                const int m = ss * 8 + sg;
                const int idx = m * 8 + r;
                const int jb = rpL[idx], je = rpL[idx + 1];
                float a[8] = {};
                int j = jb;
                int sc = (j < je) ? perm[j] : 0;
                while (j < je) {
                    int jn = (j + 1 < je) ? (j + 1) : j;
                    int sn = perm[jn];                       // prefetch next src
                    short8 row = *(const short8*)&xbf[(size_t)sc * CH + cg * 8];
                    #pragma unroll
                    for (int k = 0; k < 8; ++k) a[k] += bf2f((ushort)row[k]);
                    sc = sn;
                    ++j;
                }
                const float iv = ivL[idx];
                short8 o;
                #pragma unroll
                for (int k = 0; k < 8; ++k) o[k] = (short)f2bf(a[k] * iv);
                *(short8*)&ab[m * 72 + cg * 8] = o;
            }
            #pragma unroll
            for (int s = 0; s < 2; ++s) {
                short8 av = *(short8*)&ab[m0 * 72 + s * 32 + q * 8];
                #pragma unroll
                for (int ct = 0; ct < 4; ++ct) {
                    short8 bv = *(const short8*)&wfrag[(((size_t)(r * 2 + s) * 4 + ct) * 64 + lane) * 8];
                    acc4[ct] = __builtin_amdgcn_mfma_f32_16x16x32_bf16(av, bv, acc4[ct], 0, 0, 0);
                }
            }
        } else {
            // root: A-frag = x rows directly from global (already bf16)
            int node = min(base + m0, N - 1);
            #pragma unroll
            for (int s = 0; s < 2; ++s) {
                short8 av = *(const short8*)&xbf[(size_t)node * CH + s * 32 + q * 8];
                #pragma unroll
                for (int ct = 0; ct < 4; ++ct) {
                    short8 bv = *(const short8*)&wfrag[(((size_t)(r * 2 + s) * 4 + ct) * 64 + lane) * 8];
                    acc4[ct] = __builtin_amdgcn_mfma_f32_16x16x32_bf16(av, bv, acc4[ct], 0, 0, 0);
                }
            }
        }
    }

    // epilogue: D[row=q*4+v][col=ct*16+m0]; row = node-in-tile
    #pragma unroll
    for (int ct = 0; ct < 4; ++ct) {
        int c = ct * 16 + m0;
        float bb = b1[c];
        #pragma unroll
        for (int v = 0; v < 4; ++v) {
            int node = base + q * 4 + v;
            if (node < N)
                h[(size_t)node * CH + c] = fmaxf(acc4[ct][v] + bb, 0.f);
        }
    }
}

// ---- layer-2 collapse: s_r[c] = sum_i h[i][c]*kappa[i][r], s0 = sum_i h[i] --

__global__ __launch_bounds__(256) void kred_kernel(
    const float* __restrict__ h, const float* __restrict__ kappa,
    float* __restrict__ sacc, int N)
{
    const int lane = threadIdx.x & 63;
    const int w = threadIdx.x >> 6;
    int wave = (blockIdx.x << 2) | w;
    const int wstride = gridDim.x << 2;
    float racc[9] = {};
    for (int i = wave; i < N; i += wstride) {
        float hv = h[(size_t)i * CH + lane];
        #pragma unroll
        for (int r = 0; r < 8; ++r) racc[r] += hv * kappa[i * 8 + r];
        racc[8] += hv;
    }
    __shared__ float red[4][9][64];
    #pragma unroll
    for (int r = 0; r < 9; ++r) red[w][r][lane] = racc[r];
    __syncthreads();
    if (w == 0) {
        #pragma unroll
        for (int r = 0; r < 9; ++r) {
            float s4 = red[0][r][lane] + red[1][r][lane] + red[2][r][lane] + red[3][r][lane];
            unsafeAtomicAdd(&sacc[r * 64 + lane], s4);
        }
    }
}

// g[o] = (s0@root2 + sum_r s_r@W2[r]) / N + b2;  out = log_softmax(g)
__global__ void finalize_kernel(const float* __restrict__ sacc, const float* __restrict__ root2,
                                const float* __restrict__ W2, const float* __restrict__ b2,
                                float* __restrict__ out, float invN)
{
    __shared__ float g[16];
    int t = threadIdx.x;
    if (t < 16) {
        const float* s0 = sacc + 512;
        float acc = 0.f;
        for (int c = 0; c < 64; ++c) acc += s0[c] * root2[c * 16 + t];
        for (int r = 0; r < 8; ++r) {
            const float* sr = sacc + r * 64;
            for (int c = 0; c < 64; ++c) acc += sr[c] * W2[(r * 64 + c) * 16 + t];
        }
        g[t] = acc * invN + b2[t];
    }
    __syncthreads();
    if (t < 16) {
        float m = -1e30f;
        for (int i = 0; i < 16; ++i) m = fmaxf(m, g[i]);
        float s = 0.f;
        for (int i = 0; i < 16; ++i) s += expf(g[i] - m);
        out[t] = g[t] - (m + logf(s));
    }
}

// ---- launch -----------------------------------------------------------------

extern "C" void kernel_launch(void* const* d_in, const int* in_sizes, int n_in,
                              void* d_out, int out_size, void* d_ws, size_t ws_size,
                              hipStream_t stream)
{
    const float* x     = (const float*)d_in[0];
    const int*   eidx  = (const int*)d_in[1];
    const int*   etype = (const int*)d_in[2];
    const float* W1    = (const float*)d_in[3];
    const float* root1 = (const float*)d_in[4];
    const float* b1    = (const float*)d_in[5];
    const float* W2    = (const float*)d_in[6];
    const float* root2 = (const float*)d_in[7];
    const float* b2    = (const float*)d_in[8];
    float* out = (float*)d_out;

    const int E = in_sizes[1] / 2;
    const int N = in_sizes[0] / CH;
    const int NKEY = N * 8;
    const int* srcI = eidx;
    const int* dstI = eidx + E;

    // workspace layout (4B units):
    // [cnt NKEY | sacc 576 | kappa NKEY | inv NKEY | rowptr NKEY+1 | cursor NKEY
    //  | bsum 1024 | perm E | pad | xbf N*CH/2 | wfrag | h N*CH]
    int* wsi = (int*)d_ws;
    int*   cnt    = wsi;
    float* sacc   = (float*)(cnt + NKEY);          // s_r [0,512), s0 [512,576)
    float* kappa  = (float*)(sacc + 576);
    float* inv    = kappa + NKEY;
    int*   rowptr = (int*)(inv + NKEY);            // NKEY+1
    int*   cursor = rowptr + NKEY + 1;
    int*   bsum   = cursor + NKEY;
    int*   perm   = bsum + 1024;
    size_t off = (size_t)((perm + E) - wsi);
    off = (off + 7) & ~(size_t)7;                  // 32B-align
    ushort* xbf  = (ushort*)(wsi + off);           // N*CH ushorts
    ushort* wfg  = xbf + (size_t)N * CH;           // 36864 ushorts
    float*  h    = (float*)(wfg + 36864);

    // zero cnt + sacc + kappa (contiguous prefix)
    hipMemsetAsync(d_ws, 0, (size_t)(NKEY + 576 + NKEY) * 4, stream);

    count_kernel<<<(E + 255) / 256, 256, 0, stream>>>(dstI, etype, cnt, E);
    inv_kernel<<<(NKEY + 255) / 256, 256, 0, stream>>>(cnt, inv, NKEY);

    const int NB1 = (NKEY + 1023) / 1024;
    scan1_kernel<<<NB1, 256, 0, stream>>>(cnt, rowptr, bsum, NKEY);
    scan2_kernel<<<1, 1024, 0, stream>>>(bsum, NB1);
    scan3_kernel<<<NB1, 256, 0, stream>>>(rowptr, cursor, bsum, NKEY, E);
    place_kernel<<<(E + 255) / 256, 256, 0, stream>>>(srcI, dstI, etype, cursor, inv, kappa, perm, E);

    xbf_kernel<<<((N * CH / 4) + 255) / 256, 256, 0, stream>>>(x, xbf, N * CH / 4);
    wfrag_kernel<<<(36864 + 255) / 256, 256, 0, stream>>>(W1, root1, wfg);

    const int tiles = (N + 15) / 16;
    rgcn1_fused_kernel<<<(tiles + 3) / 4, 256, 0, stream>>>(
        rowptr, perm, inv, xbf, wfg, b1, h, N, NKEY);

    kred_kernel<<<1024, 256, 0, stream>>>(h, kappa, sacc, N);
    finalize_kernel<<<1, 64, 0, stream>>>(sacc, root2, W2, b2, out, 1.0f / (float)N);
}

// Round 6
// 396.258 us; speedup vs baseline: 3.3858x; 1.2500x over previous
//
#include <hip/hip_runtime.h>
#include <hip/hip_bf16.h>

// RGCN 2-layer + global mean pool + log_softmax. Round 6.
// Preprocessing rebuilt as locality-partitioned two-level counting sort:
//   bin:   block-local LDS sort by coarse bucket (dst>>9), chunked 8B writes
//   scanb: 256-entry bucket-count scan
//   build: one WG per bucket: LDS hist (4096 local keys) + LDS scan ->
//          coalesced rowptr/inv, LDS-cursor placement into a 32KB perm window
//          (single-XCD locality), kappa atomics fused in.
// Layer 1: fused MFMA kernel (unchanged from R5). Layer 2: kappa collapse.

#define CH 64
#define BK_EDGES 2048
#define BUCKET_SHIFT 9
#define CAP 12288   // per-bucket record capacity (avg fill ~8200, >40 sigma)

typedef __attribute__((ext_vector_type(8))) short short8;
typedef __attribute__((ext_vector_type(4))) float f32x4;

__device__ inline ushort f2bf(float f) {
    unsigned b = __float_as_uint(f);
    unsigned r = (b + 0x7FFFu + ((b >> 16) & 1u)) >> 16;
    return (ushort)r;
}
__device__ inline float bf2f(ushort u) {
    return __uint_as_float(((unsigned)u) << 16);
}

// ---- preprocessing ----------------------------------------------------------

// Block-local counting sort by coarse bucket, then run-contiguous global writes.
__global__ __launch_bounds__(256) void bin_kernel(
    const int* __restrict__ src, const int* __restrict__ dst,
    const int* __restrict__ etype, int* __restrict__ gBucketCnt,
    int2* __restrict__ bucket_buf, int E)
{
    __shared__ int s_dr[BK_EDGES];
    __shared__ int s_sr[BK_EDGES];
    __shared__ int hist[256], scanv[256], lcur[256], bstart[256], gbase[256];
    const int t = threadIdx.x;
    const int e0 = blockIdx.x * BK_EDGES;
    const int cnt = min(BK_EDGES, E - e0);

    hist[t] = 0;
    __syncthreads();

    int myb[8], mydr[8], mysr[8];
    #pragma unroll
    for (int i = 0; i < 8; ++i) {
        int li = t + i * 256;
        if (li < cnt) {
            int e = e0 + li;
            int d = dst[e];
            mydr[i] = (d << 3) | etype[e];
            mysr[i] = src[e];
            myb[i] = d >> BUCKET_SHIFT;
            atomicAdd(&hist[myb[i]], 1);
        } else myb[i] = -1;
    }
    __syncthreads();

    int v = hist[t];
    scanv[t] = v;
    __syncthreads();
    for (int off = 1; off < 256; off <<= 1) {
        int u = (t >= off) ? scanv[t - off] : 0;
        __syncthreads();
        scanv[t] += u;
        __syncthreads();
    }
    int excl = scanv[t] - v;
    bstart[t] = excl;
    lcur[t] = excl;
    __syncthreads();

    #pragma unroll
    for (int i = 0; i < 8; ++i) {
        if (myb[i] >= 0) {
            int p = atomicAdd(&lcur[myb[i]], 1);
            s_dr[p] = mydr[i];
            s_sr[p] = mysr[i];
        }
    }
    __syncthreads();

    if (v > 0) gbase[t] = atomicAdd(&gBucketCnt[t], v);
    __syncthreads();

    for (int p = t; p < cnt; p += 256) {
        int dr = s_dr[p];
        int b = dr >> 12;                       // == dst >> 9
        int gp = gbase[b] + (p - bstart[b]);
        if (gp < CAP)
            bucket_buf[(size_t)b * CAP + gp] = make_int2(dr, s_sr[p]);
    }
}

// exclusive scan of 256 bucket counts
__global__ __launch_bounds__(256) void scanb_kernel(const int* __restrict__ gBucketCnt,
                                                    int* __restrict__ gBucketBase) {
    __shared__ int ts[256];
    int t = threadIdx.x;
    int v = gBucketCnt[t];
    ts[t] = v;
    __syncthreads();
    for (int off = 1; off < 256; off <<= 1) {
        int u = (t >= off) ? ts[t - off] : 0;
        __syncthreads();
        ts[t] += u;
        __syncthreads();
    }
    gBucketBase[t] = ts[t] - v;
}

// One workgroup per bucket: LDS hist + scan over 4096 local keys, coalesced
// rowptr/inv writes, LDS-cursor placement (perm window ~32KB, single XCD),
// fused kappa atomics.
__global__ __launch_bounds__(256) void build_kernel(
    const int2* __restrict__ bucket_buf, const int* __restrict__ gBucketCnt,
    const int* __restrict__ gBucketBase, int* __restrict__ rowptr,
    float* __restrict__ inv, int* __restrict__ perm, float* __restrict__ kappa)
{
    __shared__ int hist[4096];
    __shared__ int cur[4096];
    __shared__ int part[256];
    const int b = blockIdx.x;
    const int t = threadIdx.x;
    const int nb = min(gBucketCnt[b], CAP);
    const int base = gBucketBase[b];
    const int2* rec = bucket_buf + (size_t)b * CAP;

    for (int i = t; i < 4096; i += 256) hist[i] = 0;
    __syncthreads();
    for (int j = t; j < nb; j += 256) atomicAdd(&hist[rec[j].x & 4095], 1);
    __syncthreads();

    const int i0 = t * 16;
    int s = 0;
    #pragma unroll
    for (int k = 0; k < 16; ++k) s += hist[i0 + k];
    part[t] = s;
    __syncthreads();
    for (int off = 1; off < 256; off <<= 1) {
        int u = (t >= off) ? part[t - off] : 0;
        __syncthreads();
        part[t] += u;
        __syncthreads();
    }
    int run = base + part[t] - s;  // global exclusive prefix
    #pragma unroll
    for (int k = 0; k < 16; ++k) {
        int c = hist[i0 + k];
        cur[i0 + k] = run;
        rowptr[b * 4096 + i0 + k] = run;
        inv[b * 4096 + i0 + k] = 1.0f / (float)max(c, 1);
        run += c;
    }
    __syncthreads();

    for (int j = t; j < nb; j += 256) {
        int dr = rec[j].x, sr = rec[j].y;
        int lk = dr & 4095;
        int pos = atomicAdd(&cur[lk], 1);   // LDS atomic
        perm[pos] = sr;
        float iv = 1.0f / (float)max(hist[lk], 1);
        unsafeAtomicAdd(&kappa[(sr << 3) | (dr & 7)], iv);
    }
}

// bf16 copy of x
__global__ void xbf_kernel(const float* __restrict__ x, ushort* __restrict__ xbf, int n4) {
    int i = blockIdx.x * blockDim.x + threadIdx.x;
    if (i < n4) {
        float4 v = ((const float4*)x)[i];
        ushort4 o = make_ushort4(f2bf(v.x), f2bf(v.y), f2bf(v.z), f2bf(v.w));
        ((ushort4*)xbf)[i] = o;
    }
}

// pre-swizzle 9 weight matrices (W1[0..7], root1) into bf16 B-fragment layout
__global__ void wfrag_kernel(const float* __restrict__ W1, const float* __restrict__ root1,
                             ushort* __restrict__ wf) {
    int idx = blockIdx.x * blockDim.x + threadIdx.x;
    if (idx >= 9 * 2 * 4 * 64 * 8) return;
    int j    = idx & 7;
    int lane = (idx >> 3) & 63;
    int ct   = (idx >> 9) & 3;
    int ks   = (idx >> 11) & 1;
    int rel  = idx >> 12;
    int k = ks * 32 + (lane >> 4) * 8 + j;
    int n = ct * 16 + (lane & 15);
    float v = (rel < 8) ? W1[((size_t)rel * 64 + k) * 64 + n] : root1[(size_t)k * 64 + n];
    wf[idx] = f2bf(v);
}

// ---- fused layer 1 (unchanged from R5) --------------------------------------

__global__ __launch_bounds__(256) void rgcn1_fused_kernel(
    const int* __restrict__ rowptr, const int* __restrict__ perm,
    const float* __restrict__ inv, const ushort* __restrict__ xbf,
    const ushort* __restrict__ wfrag, const float* __restrict__ b1,
    float* __restrict__ h, int N, int NKEY)
{
    __shared__ ushort Abuf[4][16 * 72];
    __shared__ int    rpS[4][132];
    __shared__ float  invS[4][128];
    const int widx = threadIdx.x >> 6;
    const int lane = threadIdx.x & 63;
    const int wid = (blockIdx.x << 2) | widx;
    const int base = wid << 4;
    if (base >= N) return;

    const int m0 = lane & 15;
    const int q  = lane >> 4;
    const int sg = lane >> 3;
    const int cg = lane & 7;
    ushort* ab = Abuf[widx];
    int*    rpL = rpS[widx];
    float*  ivL = invS[widx];

    const int key0 = base * 8;
    rpL[lane]      = rowptr[min(key0 + lane, NKEY)];
    rpL[64 + lane] = rowptr[min(key0 + 64 + lane, NKEY)];
    if (lane == 0) rpL[128] = rowptr[min(key0 + 128, NKEY)];
    ivL[lane]      = inv[min(key0 + lane, NKEY - 1)];
    ivL[64 + lane] = inv[min(key0 + 64 + lane, NKEY - 1)];

    f32x4 acc4[4];
    #pragma unroll
    for (int ct = 0; ct < 4; ++ct) acc4[ct] = (f32x4)(0.0f);

    for (int r = 0; r < 9; ++r) {
        if (r < 8) {
            #pragma unroll
            for (int ss = 0; ss < 2; ++ss) {
                const int m = ss * 8 + sg;
                const int idx = m * 8 + r;
                const int jb = rpL[idx], je = rpL[idx + 1];
                float a[8] = {};
                int j = jb;
                int sc = (j < je) ? perm[j] : 0;
                while (j < je) {
                    int jn = (j + 1 < je) ? (j + 1) : j;
                    int sn = perm[jn];
                    short8 row = *(const short8*)&xbf[(size_t)sc * CH + cg * 8];
                    #pragma unroll
                    for (int k = 0; k < 8; ++k) a[k] += bf2f((ushort)row[k]);
                    sc = sn;
                    ++j;
                }
                const float iv = ivL[idx];
                short8 o;
                #pragma unroll
                for (int k = 0; k < 8; ++k) o[k] = (short)f2bf(a[k] * iv);
                *(short8*)&ab[m * 72 + cg * 8] = o;
            }
            #pragma unroll
            for (int s = 0; s < 2; ++s) {
                short8 av = *(short8*)&ab[m0 * 72 + s * 32 + q * 8];
                #pragma unroll
                for (int ct = 0; ct < 4; ++ct) {
                    short8 bv = *(const short8*)&wfrag[(((size_t)(r * 2 + s) * 4 + ct) * 64 + lane) * 8];
                    acc4[ct] = __builtin_amdgcn_mfma_f32_16x16x32_bf16(av, bv, acc4[ct], 0, 0, 0);
                }
            }
        } else {
            int node = min(base + m0, N - 1);
            #pragma unroll
            for (int s = 0; s < 2; ++s) {
                short8 av = *(const short8*)&xbf[(size_t)node * CH + s * 32 + q * 8];
                #pragma unroll
                for (int ct = 0; ct < 4; ++ct) {
                    short8 bv = *(const short8*)&wfrag[(((size_t)(r * 2 + s) * 4 + ct) * 64 + lane) * 8];
                    acc4[ct] = __builtin_amdgcn_mfma_f32_16x16x32_bf16(av, bv, acc4[ct], 0, 0, 0);
                }
            }
        }
    }

    #pragma unroll
    for (int ct = 0; ct < 4; ++ct) {
        int c = ct * 16 + m0;
        float bb = b1[c];
        #pragma unroll
        for (int v = 0; v < 4; ++v) {
            int node = base + q * 4 + v;
            if (node < N)
                h[(size_t)node * CH + c] = fmaxf(acc4[ct][v] + bb, 0.f);
        }
    }
}

// ---- layer-2 collapse -------------------------------------------------------

__global__ __launch_bounds__(256) void kred_kernel(
    const float* __restrict__ h, const float* __restrict__ kappa,
    float* __restrict__ sacc, int N)
{
    const int lane = threadIdx.x & 63;
    const int w = threadIdx.x >> 6;
    int wave = (blockIdx.x << 2) | w;
    const int wstride = gridDim.x << 2;
    float racc[9] = {};
    for (int i = wave; i < N; i += wstride) {
        float hv = h[(size_t)i * CH + lane];
        #pragma unroll
        for (int r = 0; r < 8; ++r) racc[r] += hv * kappa[i * 8 + r];
        racc[8] += hv;
    }
    __shared__ float red[4][9][64];
    #pragma unroll
    for (int r = 0; r < 9; ++r) red[w][r][lane] = racc[r];
    __syncthreads();
    if (w == 0) {
        #pragma unroll
        for (int r = 0; r < 9; ++r) {
            float s4 = red[0][r][lane] + red[1][r][lane] + red[2][r][lane] + red[3][r][lane];
            unsafeAtomicAdd(&sacc[r * 64 + lane], s4);
        }
    }
}

__global__ void finalize_kernel(const float* __restrict__ sacc, const float* __restrict__ root2,
                                const float* __restrict__ W2, const float* __restrict__ b2,
                                float* __restrict__ out, float invN)
{
    __shared__ float g[16];
    int t = threadIdx.x;
    if (t < 16) {
        const float* s0 = sacc + 512;
        float acc = 0.f;
        for (int c = 0; c < 64; ++c) acc += s0[c] * root2[c * 16 + t];
        for (int r = 0; r < 8; ++r) {
            const float* sr = sacc + r * 64;
            for (int c = 0; c < 64; ++c) acc += sr[c] * W2[(r * 64 + c) * 16 + t];
        }
        g[t] = acc * invN + b2[t];
    }
    __syncthreads();
    if (t < 16) {
        float m = -1e30f;
        for (int i = 0; i < 16; ++i) m = fmaxf(m, g[i]);
        float s = 0.f;
        for (int i = 0; i < 16; ++i) s += expf(g[i] - m);
        out[t] = g[t] - (m + logf(s));
    }
}

// ---- launch -----------------------------------------------------------------

extern "C" void kernel_launch(void* const* d_in, const int* in_sizes, int n_in,
                              void* d_out, int out_size, void* d_ws, size_t ws_size,
                              hipStream_t stream)
{
    const float* x     = (const float*)d_in[0];
    const int*   eidx  = (const int*)d_in[1];
    const int*   etype = (const int*)d_in[2];
    const float* W1    = (const float*)d_in[3];
    const float* root1 = (const float*)d_in[4];
    const float* b1    = (const float*)d_in[5];
    const float* W2    = (const float*)d_in[6];
    const float* root2 = (const float*)d_in[7];
    const float* b2    = (const float*)d_in[8];
    float* out = (float*)d_out;

    const int E = in_sizes[1] / 2;
    const int N = in_sizes[0] / CH;
    const int NKEY = N * 8;
    const int NBUK = (N + 511) >> BUCKET_SHIFT;    // 196 for N=100K (<=256)
    const int KSPACE = NBUK << 12;
    const int* srcI = eidx;
    const int* dstI = eidx + E;

    // workspace layout (4B units):
    // [gBucketCnt 256 | sacc 576 | kappa NKEY]   <- zeroed prefix
    // [gBucketBase 256 | inv KSPACE | rowptr KSPACE+16 | perm E |
    //  bucket_buf NBUK*CAP*2 (8B-aligned) | xbf N*CH/2 | wfrag | h N*CH]
    int* wsi = (int*)d_ws;
    int*   gBucketCnt  = wsi;
    float* sacc        = (float*)(gBucketCnt + 256);
    float* kappa       = sacc + 576;
    int*   gBucketBase = (int*)(kappa + NKEY);
    float* inv         = (float*)(gBucketBase + 256);
    int*   rowptr      = (int*)(inv + KSPACE);
    int*   perm        = rowptr + KSPACE + 16;
    size_t off = (size_t)((perm + E) - wsi);
    off = (off + 1) & ~(size_t)1;                  // 8B-align for int2
    int2*  bucket_buf  = (int2*)(wsi + off);
    off += (size_t)NBUK * CAP * 2;
    off = (off + 7) & ~(size_t)7;                  // 32B-align
    ushort* xbf = (ushort*)(wsi + off);            // N*CH ushorts
    ushort* wfg = xbf + (size_t)N * CH;
    float*  h   = (float*)(wfg + 36864);

    hipMemsetAsync(d_ws, 0, (size_t)(256 + 576 + NKEY) * 4, stream);

    bin_kernel<<<(E + BK_EDGES - 1) / BK_EDGES, 256, 0, stream>>>(
        srcI, dstI, etype, gBucketCnt, bucket_buf, E);
    scanb_kernel<<<1, 256, 0, stream>>>(gBucketCnt, gBucketBase);
    build_kernel<<<NBUK, 256, 0, stream>>>(
        bucket_buf, gBucketCnt, gBucketBase, rowptr, inv, perm, kappa);

    xbf_kernel<<<((N * CH / 4) + 255) / 256, 256, 0, stream>>>(x, xbf, N * CH / 4);
    wfrag_kernel<<<(36864 + 255) / 256, 256, 0, stream>>>(W1, root1, wfg);

    const int tiles = (N + 15) / 16;
    rgcn1_fused_kernel<<<(tiles + 3) / 4, 256, 0, stream>>>(
        rowptr, perm, inv, xbf, wfg, b1, h, N, NKEY);

    kred_kernel<<<1024, 256, 0, stream>>>(h, kappa, sacc, N);
    finalize_kernel<<<1, 64, 0, stream>>>(sacc, root2, W2, b2, out, 1.0f / (float)N);
}